// Round 6
// baseline (613.306 us; speedup 1.0000x reference)
//
#include <hip/hip_runtime.h>
#include <cstdint>

#define BLOCK 256
#define GRID 2048          // 8 blocks/CU x 256 CUs: persistent-style
#define UNROLL 4

typedef float f4 __attribute__((ext_vector_type(4)));

// Persistent grid-stride structure, R2's proven per-tile scheme:
//  - lane loads float4 (16B, fully coalesced across lanes)
//  - one element's 32 spikes span 8 consecutive lanes (4 bits/lane),
//    nibble pre-shifted into IEEE MSB-first position, OR-butterfly
//    (__shfl_xor 1,2,4) assembles the word in all 8 lanes
//  - redundant IEEE fp32 multiply, each lane unpacks its own 4 bits,
//    coalesced float4 store.
//  - 8 outer iters x UNROLL independent tiles, loads batched -> steady-state
//    streaming, no block-dispatch churn.
__global__ __launch_bounds__(BLOCK) void spikefp32mul_kernel(
    const f4* __restrict__ A4, const f4* __restrict__ B4,
    f4* __restrict__ O4, int n4)
{
    const int T = GRID * BLOCK;                       // total threads = 524288
    const int tid = blockIdx.x * BLOCK + threadIdx.x;
    const int sb = 28 - 4 * (tid & 7);                // stride T ≡ 0 (mod 8)

    const int iters = n4 / (T * UNROLL);              // 8 at this size, exact

    for (int t = 0; t < iters; ++t) {
        int base = tid + t * (T * UNROLL);

        f4 a[UNROLL], b[UNROLL];
#pragma unroll
        for (int j = 0; j < UNROLL; ++j) {
            a[j] = A4[base + j * T];
            b[j] = B4[base + j * T];
        }

#pragma unroll
        for (int j = 0; j < UNROLL; ++j) {
            uint32_t wa = ((a[j].x > 0.5f ? 8u : 0u) | (a[j].y > 0.5f ? 4u : 0u) |
                           (a[j].z > 0.5f ? 2u : 0u) | (a[j].w > 0.5f ? 1u : 0u)) << sb;
            uint32_t wb = ((b[j].x > 0.5f ? 8u : 0u) | (b[j].y > 0.5f ? 4u : 0u) |
                           (b[j].z > 0.5f ? 2u : 0u) | (b[j].w > 0.5f ? 1u : 0u)) << sb;

            wa |= (uint32_t)__shfl_xor((int)wa, 1, 64);
            wb |= (uint32_t)__shfl_xor((int)wb, 1, 64);
            wa |= (uint32_t)__shfl_xor((int)wa, 2, 64);
            wb |= (uint32_t)__shfl_xor((int)wb, 2, 64);
            wa |= (uint32_t)__shfl_xor((int)wa, 4, 64);
            wb |= (uint32_t)__shfl_xor((int)wb, 4, 64);

            float p = __uint_as_float(wa) * __uint_as_float(wb);  // IEEE RNE
            uint32_t wp = __float_as_uint(p);

            f4 o;
            o.x = (float)((wp >> (sb + 3)) & 1u);
            o.y = (float)((wp >> (sb + 2)) & 1u);
            o.z = (float)((wp >> (sb + 1)) & 1u);
            o.w = (float)((wp >> sb) & 1u);
            O4[base + j * T] = o;
        }
    }

    // Remainder tiles (none at this problem size: 16,777,216 = 524288*32).
    for (int g = iters * (T * UNROLL) + tid; g < n4; g += T) {
        f4 a = A4[g], b = B4[g];
        uint32_t wa = ((a.x > 0.5f ? 8u : 0u) | (a.y > 0.5f ? 4u : 0u) |
                       (a.z > 0.5f ? 2u : 0u) | (a.w > 0.5f ? 1u : 0u)) << sb;
        uint32_t wb = ((b.x > 0.5f ? 8u : 0u) | (b.y > 0.5f ? 4u : 0u) |
                       (b.z > 0.5f ? 2u : 0u) | (b.w > 0.5f ? 1u : 0u)) << sb;
        wa |= (uint32_t)__shfl_xor((int)wa, 1, 64);
        wb |= (uint32_t)__shfl_xor((int)wb, 1, 64);
        wa |= (uint32_t)__shfl_xor((int)wa, 2, 64);
        wb |= (uint32_t)__shfl_xor((int)wb, 2, 64);
        wa |= (uint32_t)__shfl_xor((int)wa, 4, 64);
        wb |= (uint32_t)__shfl_xor((int)wb, 4, 64);
        float p = __uint_as_float(wa) * __uint_as_float(wb);
        uint32_t wp = __float_as_uint(p);
        f4 o;
        o.x = (float)((wp >> (sb + 3)) & 1u);
        o.y = (float)((wp >> (sb + 2)) & 1u);
        o.z = (float)((wp >> (sb + 1)) & 1u);
        o.w = (float)((wp >> sb) & 1u);
        O4[g] = o;
    }
}

extern "C" void kernel_launch(void* const* d_in, const int* in_sizes, int n_in,
                              void* d_out, int out_size, void* d_ws, size_t ws_size,
                              hipStream_t stream) {
    const f4* A4 = (const f4*)d_in[0];
    const f4* B4 = (const f4*)d_in[1];
    f4* O4 = (f4*)d_out;

    int n4 = in_sizes[0] / 4;   // 16,777,216 float4 tiles
    spikefp32mul_kernel<<<GRID, BLOCK, 0, stream>>>(A4, B4, O4, n4);
}

// Round 7
// 571.652 us; speedup vs baseline: 1.0729x; 1.0729x over previous
//
#include <hip/hip_runtime.h>
#include <cstdint>

#define BLOCK 256

typedef float f4 __attribute__((ext_vector_type(4)));

// R2 structure exactly (best measured: 175 us), single change: nontemporal
// store. Lane i loads float4 #i (fully coalesced). One element's 32 spike
// floats span 8 consecutive lanes (4 bits/lane). Pack nibble pre-shifted into
// IEEE MSB-first position, OR-butterfly (__shfl_xor 1,2,4) assembles the word
// in all 8 lanes, redundant IEEE fp32 multiply, each lane unpacks its own 4
// output bits -> coalesced nt float4 store.
__global__ __launch_bounds__(BLOCK) void spikefp32mul_kernel(
    const f4* __restrict__ A4, const f4* __restrict__ B4,
    f4* __restrict__ O4, int n4)
{
    int g = blockIdx.x * BLOCK + threadIdx.x;
    if (g >= n4) return;

    f4 a = A4[g];
    f4 b = B4[g];

    // float index f = 4g + c belongs to element g/8, bit j = f%32 = 4*(g&7)+c,
    // which is IEEE bit 31-j. Nibble base shift:
    const int sb = 28 - 4 * (g & 7);

    uint32_t wa = ((a.x > 0.5f ? 8u : 0u) | (a.y > 0.5f ? 4u : 0u) |
                   (a.z > 0.5f ? 2u : 0u) | (a.w > 0.5f ? 1u : 0u)) << sb;
    uint32_t wb = ((b.x > 0.5f ? 8u : 0u) | (b.y > 0.5f ? 4u : 0u) |
                   (b.z > 0.5f ? 2u : 0u) | (b.w > 0.5f ? 1u : 0u)) << sb;

    // OR-butterfly across the 8 lanes of this element group.
    wa |= (uint32_t)__shfl_xor((int)wa, 1, 64);
    wb |= (uint32_t)__shfl_xor((int)wb, 1, 64);
    wa |= (uint32_t)__shfl_xor((int)wa, 2, 64);
    wb |= (uint32_t)__shfl_xor((int)wb, 2, 64);
    wa |= (uint32_t)__shfl_xor((int)wa, 4, 64);
    wb |= (uint32_t)__shfl_xor((int)wb, 4, 64);

    float p = __uint_as_float(wa) * __uint_as_float(wb);  // IEEE fp32 mul, RNE
    uint32_t wp = __float_as_uint(p);

    f4 o;
    o.x = (float)((wp >> (sb + 3)) & 1u);
    o.y = (float)((wp >> (sb + 2)) & 1u);
    o.z = (float)((wp >> (sb + 1)) & 1u);
    o.w = (float)((wp >> sb) & 1u);
    __builtin_nontemporal_store(o, &O4[g]);
}

extern "C" void kernel_launch(void* const* d_in, const int* in_sizes, int n_in,
                              void* d_out, int out_size, void* d_ws, size_t ws_size,
                              hipStream_t stream) {
    const f4* A4 = (const f4*)d_in[0];
    const f4* B4 = (const f4*)d_in[1];
    f4* O4 = (f4*)d_out;

    int n4 = in_sizes[0] / 4;   // 16,777,216 float4s; 65536 blocks of 256
    const int grid = (n4 + BLOCK - 1) / BLOCK;
    spikefp32mul_kernel<<<grid, BLOCK, 0, stream>>>(A4, B4, O4, n4);
}